// Round 1
// 500.295 us; speedup vs baseline: 1.0141x; 1.0141x over previous
//
#include <hip/hip_runtime.h>
#include <math.h>

#define BATCH 64
#define IN_DIM 512
#define MEM 1024

typedef float f32x4 __attribute__((ext_vector_type(4)));

// ---------------------------------------------------------------------------
// Kernel 1: gates. out[g][b][m] = act_g( sum_k x[b,k]*W_g[m,k] + bias_g[m] )
// grid 192 x 256. Each wave handles 8 consecutive output columns (gm), lane=b.
// x chunk staged TRANSPOSED in LDS; W rows via wave-uniform (scalar) loads.
// unroll 2 (was 4): keep live W registers <= 64 to avoid spill.
// (unchanged this round — isolating the update_kernel restructure)
// ---------------------------------------------------------------------------
__global__ __launch_bounds__(256)
void gates_kernel(const float* __restrict__ x,
                  const float* __restrict__ Wq, const float* __restrict__ bq,
                  const float* __restrict__ Wk, const float* __restrict__ bk,
                  const float* __restrict__ Wv, const float* __restrict__ bv,
                  const float* __restrict__ Wi, const float* __restrict__ bi,
                  const float* __restrict__ Wf, const float* __restrict__ bf,
                  const float* __restrict__ Wo, const float* __restrict__ bo,
                  float* __restrict__ gates /* [6][BATCH][MEM] */) {
    __shared__ float xs[64][65];   // xs[k_local][b]
    const int t    = threadIdx.x;
    const int lane = t & 63;                                    // = batch b
    const int wave = __builtin_amdgcn_readfirstlane(t >> 6);    // SGPR
    const int gm0  = blockIdx.x * 32 + wave * 8;                // col base
    const int g    = gm0 >> 10;                                 // gate id
    const int m0   = gm0 & 1023;

    const float* W; const float* bias;
    switch (g) {
        case 0: W = Wq; bias = bq; break;
        case 1: W = Wk; bias = bk; break;
        case 2: W = Wv; bias = bv; break;
        case 3: W = Wi; bias = bi; break;
        case 4: W = Wf; bias = bf; break;
        default: W = Wo; bias = bo; break;
    }

    float acc[8];
#pragma unroll
    for (int j = 0; j < 8; ++j) acc[j] = 0.f;

    for (int kk = 0; kk < IN_DIM; kk += 64) {
        __syncthreads();
        // cooperative load of x[:, kk:kk+64], transposed into LDS
#pragma unroll
        for (int j = 0; j < 4; ++j) {
            int ii = t + j * 256;          // 1024 float4 total
            int bb = ii >> 4;              // batch row
            int c4 = ii & 15;              // float4 within chunk
            float4 v = *(const float4*)&x[bb * IN_DIM + kk + c4 * 4];
            xs[c4 * 4 + 0][bb] = v.x;
            xs[c4 * 4 + 1][bb] = v.y;
            xs[c4 * 4 + 2][bb] = v.z;
            xs[c4 * 4 + 3][bb] = v.w;
        }
        __syncthreads();

        const float* wp = W + (size_t)m0 * IN_DIM + kk;
#pragma unroll 2
        for (int k4 = 0; k4 < 16; ++k4) {
            float4 wv[8];
#pragma unroll
            for (int j = 0; j < 8; ++j)
                wv[j] = *(const float4*)(wp + j * IN_DIM + k4 * 4);
            float x0 = xs[k4 * 4 + 0][lane];
            float x1 = xs[k4 * 4 + 1][lane];
            float x2 = xs[k4 * 4 + 2][lane];
            float x3 = xs[k4 * 4 + 3][lane];
#pragma unroll
            for (int j = 0; j < 8; ++j) {
                acc[j] = fmaf(x0, wv[j].x, acc[j]);
                acc[j] = fmaf(x1, wv[j].y, acc[j]);
                acc[j] = fmaf(x2, wv[j].z, acc[j]);
                acc[j] = fmaf(x3, wv[j].w, acc[j]);
            }
        }
    }

    // epilogue: bias + activation, store [g][b=lane][m0..m0+7] as 2 float4
    float v[8];
#pragma unroll
    for (int j = 0; j < 8; ++j) {
        float val = acc[j] + bias[m0 + j];
        if (g == 1)      val *= 0.03125f;                  // k / sqrt(M)
        else if (g == 3) val = __expf(val);                // exponential gate i
        else if (g >= 4) val = 1.f / (1.f + __expf(-val)); // sigmoid f, o
        v[j] = val;
    }
    float* outp = gates + (size_t)g * BATCH * MEM + (size_t)lane * MEM + m0;
    *(float4*)(outp + 0) = make_float4(v[0], v[1], v[2], v[3]);
    *(float4*)(outp + 4) = make_float4(v[4], v[5], v[6], v[7]);
}

// ---------------------------------------------------------------------------
// Kernel 2: n_t = f*n_prev + i*k ; denom[b] = max(n_t . q, 1)
// grid 64 (one block per batch) x 256   (unchanged)
// ---------------------------------------------------------------------------
__global__ __launch_bounds__(256)
void nt_denom_kernel(const float* __restrict__ gates,
                     const float* __restrict__ n_prev,
                     float* __restrict__ n_out,
                     float* __restrict__ denom) {
    const int b = blockIdx.x;
    const int t = threadIdx.x;
    const float* q  = gates + 0 * BATCH * MEM + (size_t)b * MEM;
    const float* k  = gates + 1 * BATCH * MEM + (size_t)b * MEM;
    const float* ig = gates + 3 * BATCH * MEM + (size_t)b * MEM;
    const float* fg = gates + 4 * BATCH * MEM + (size_t)b * MEM;

    float part = 0.f;
#pragma unroll
    for (int j = 0; j < 4; ++j) {
        int m = t + j * 256;
        float nt = fg[m] * n_prev[(size_t)b * MEM + m] + ig[m] * k[m];
        n_out[(size_t)b * MEM + m] = nt;
        part += nt * q[m];
    }
#pragma unroll
    for (int off = 32; off; off >>= 1) part += __shfl_xor(part, off, 64);

    __shared__ float red[4];
    if ((t & 63) == 0) red[t >> 6] = part;
    __syncthreads();
    if (t == 0) denom[b] = fmaxf(red[0] + red[1] + red[2] + red[3], 1.0f);
}

// ---------------------------------------------------------------------------
// Kernel 3 (the roofline): per C-row (b,m):
//   C_t[b,m,:] = f[b,m]*C_prev[b,m,:] + (i*v)[b,m]*k[b,:]
//   h_t[b,m]   = o[b,m] * (C_t[b,m,:] . q[b,:]) / denom[b]
//
// v2 restructure for memory-level parallelism:
//   - NO LDS, NO barriers: each lane owns columns {c*64+lane} for c=0..3 and
//     keeps q/k chunks in registers (loaded once per wave from L2-hot gates).
//   - All 16 C_prev NT loads (4 rows x 4 chunks) issued before any compute:
//     row 0 computes at vmcnt(12) with 12 loads still in flight.
//   - Cross-lane reduces deferred until after all loads/stores are issued,
//     off the memory critical path.
// Per-row scalars (f, i*v, o) are wave-uniform -> scalar loads, hoisted.
// grid 4096 x 256; wave handles 4 consecutive rows; block covers 16 rows.
// ---------------------------------------------------------------------------
__global__ __launch_bounds__(256)
void update_kernel(const float* __restrict__ C_prev,
                   const float* __restrict__ gates,
                   const float* __restrict__ denom,
                   float* __restrict__ h_out,
                   float* __restrict__ C_out) {
    const int t    = threadIdx.x;
    const int wave = __builtin_amdgcn_readfirstlane(t >> 6);
    const int lane = t & 63;
    const int row0 = blockIdx.x * 16 + wave * 4;   // 4 consecutive C-rows/wave
    const int b    = row0 >> 10;
    const int m0   = row0 & 1023;

    const f32x4* qp = (const f32x4*)(gates + 0 * BATCH * MEM + (size_t)b * MEM);
    const f32x4* kp = (const f32x4*)(gates + 1 * BATCH * MEM + (size_t)b * MEM);

    // lane-owned q/k column chunks, registers for the whole wave lifetime
    f32x4 qv[4], kv[4];
#pragma unroll
    for (int c = 0; c < 4; ++c) {
        qv[c] = qp[c * 64 + lane];
        kv[c] = kp[c * 64 + lane];
    }

    // wave-uniform per-row gate scalars (compiler scalarizes: uniform address)
    float fm[4], iv[4], om[4];
#pragma unroll
    for (int r = 0; r < 4; ++r) {
        fm[r] = gates[4 * BATCH * MEM + (size_t)b * MEM + m0 + r];
        iv[r] = gates[3 * BATCH * MEM + (size_t)b * MEM + m0 + r] *
                gates[2 * BATCH * MEM + (size_t)b * MEM + m0 + r];
        om[r] = gates[5 * BATCH * MEM + (size_t)b * MEM + m0 + r];
    }
    const float inv_den = 1.0f / denom[b];

    // issue ALL 16 streaming loads before any dependent compute
    f32x4 cv[4][4];
#pragma unroll
    for (int r = 0; r < 4; ++r) {
        const f32x4* cp = (const f32x4*)(C_prev + (size_t)(row0 + r) * MEM);
#pragma unroll
        for (int c = 0; c < 4; ++c)
            cv[r][c] = __builtin_nontemporal_load(&cp[c * 64 + lane]);
    }

    float acc[4];
#pragma unroll
    for (int r = 0; r < 4; ++r) {
        f32x4* co = (f32x4*)(C_out + (size_t)(row0 + r) * MEM);
        float a = 0.f;
#pragma unroll
        for (int c = 0; c < 4; ++c) {
            f32x4 ct;
            ct.x = fmaf(fm[r], cv[r][c].x, iv[r] * kv[c].x);
            ct.y = fmaf(fm[r], cv[r][c].y, iv[r] * kv[c].y);
            ct.z = fmaf(fm[r], cv[r][c].z, iv[r] * kv[c].z);
            ct.w = fmaf(fm[r], cv[r][c].w, iv[r] * kv[c].w);
            __builtin_nontemporal_store(ct, &co[c * 64 + lane]);
            a = fmaf(ct.x, qv[c].x, a);
            a = fmaf(ct.y, qv[c].y, a);
            a = fmaf(ct.z, qv[c].z, a);
            a = fmaf(ct.w, qv[c].w, a);
        }
        acc[r] = a;
    }

    // deferred cross-lane reduces (off the streaming critical path)
#pragma unroll
    for (int r = 0; r < 4; ++r)
#pragma unroll
        for (int off = 32; off; off >>= 1)
            acc[r] += __shfl_xor(acc[r], off, 64);

    if (lane == 0) {
#pragma unroll
        for (int r = 0; r < 4; ++r)
            h_out[row0 + r] = om[r] * acc[r] * inv_den;
    }
}

// ---------------------------------------------------------------------------
extern "C" void kernel_launch(void* const* d_in, const int* in_sizes, int n_in,
                              void* d_out, int out_size, void* d_ws, size_t ws_size,
                              hipStream_t stream) {
    const float* x      = (const float*)d_in[0];
    const float* C_prev = (const float*)d_in[3];
    const float* n_prev = (const float*)d_in[4];
    const float* Wq = (const float*)d_in[6];  const float* bq = (const float*)d_in[7];
    const float* Wk = (const float*)d_in[8];  const float* bk = (const float*)d_in[9];
    const float* Wv = (const float*)d_in[10]; const float* bv = (const float*)d_in[11];
    const float* Wi = (const float*)d_in[12]; const float* bi = (const float*)d_in[13];
    const float* Wf = (const float*)d_in[14]; const float* bf = (const float*)d_in[15];
    const float* Wo = (const float*)d_in[16]; const float* bo = (const float*)d_in[17];

    float* h_out = (float*)d_out;                       // [64,1024]
    float* C_out = h_out + BATCH * MEM;                 // [64,1024,1024]
    float* n_out = C_out + (size_t)BATCH * MEM * MEM;   // [64,1024]

    float* gates = (float*)d_ws;                        // 6 * 64 * 1024 floats
    float* denom = gates + 6 * BATCH * MEM;             // 64 floats

    gates_kernel<<<192, 256, 0, stream>>>(x, Wq, bq, Wk, bk, Wv, bv,
                                          Wi, bi, Wf, bf, Wo, bo, gates);
    nt_denom_kernel<<<64, 256, 0, stream>>>(gates, n_prev, n_out, denom);
    update_kernel<<<4096, 256, 0, stream>>>(C_prev, gates, denom, h_out, C_out);
}